// Round 3
// baseline (138.315 us; speedup 1.0000x reference)
//
#include <hip/hip_runtime.h>
#include <hip/hip_bf16.h>

#define HEADS 12
#define HD 64
#define PADW 32
#define EMBED 768
#define LSEQ 2048
#define QKV_N (3 * HEADS * HD)   // 2304
#define LPAD (LSEQ + 64)         // 2112, vT padded l-extent

typedef short short8 __attribute__((ext_vector_type(8)));
typedef short short4v __attribute__((ext_vector_type(4)));
typedef float f32x4 __attribute__((ext_vector_type(4)));

// Static scratch, fully overwritten every call (poison-safe).
__device__ short g_xb[LSEQ * EMBED];        // x bf16             [2048][768]
__device__ short g_wqkvT[QKV_N * EMBED];    // w_qkv^T bf16       [2304][768]
__device__ short g_woutT[EMBED * EMBED];    // w_out^T bf16       [768][768]
__device__ short g_qkvb[LSEQ * QKV_N];      // qkv bf16           [2048][2304]
__device__ short g_vT[HEADS * HD * LPAD];   // V^T bf16, 0-padded [12][64][2112]
__device__ short g_attnb[LSEQ * EMBED];     // attn out bf16      [2048][768]

__device__ __forceinline__ short f2bf(float f) {
  unsigned x = __builtin_bit_cast(unsigned, f);
  x += 0x7fffu + ((x >> 16) & 1u);   // RNE
  return (short)(x >> 16);
}

#define GLB(p) ((const __attribute__((address_space(1))) void*)(p))
#define LDS(p) ((__attribute__((address_space(3))) void*)(p))

// ---------------------------------------------------------------------------
// prep kernels
// ---------------------------------------------------------------------------
__global__ __launch_bounds__(256) void cast_bf16(const float* __restrict__ in,
                                                 short* __restrict__ out) {
  int i = blockIdx.x * 256 + threadIdx.x;
  float4 v = ((const float4*)in)[i];
  short4v o;
  o[0] = f2bf(v.x); o[1] = f2bf(v.y); o[2] = f2bf(v.z); o[3] = f2bf(v.w);
  ((short4v*)out)[i] = o;
}

// W[K][N] fp32 -> WT[N][K] bf16
__global__ __launch_bounds__(256) void transpose_cast(
    const float* __restrict__ W, short* __restrict__ WT, int K, int N) {
  __shared__ float T[32][33];
  int tx = threadIdx.x & 31, ty = threadIdx.x >> 5;
  int n0 = blockIdx.x * 32, k0 = blockIdx.y * 32;
#pragma unroll
  for (int p = 0; p < 4; ++p)
    T[ty + p * 8][tx] = W[(size_t)(k0 + ty + p * 8) * N + n0 + tx];
  __syncthreads();
#pragma unroll
  for (int p = 0; p < 4; ++p)
    WT[(size_t)(n0 + ty + p * 8) * K + k0 + tx] = f2bf(T[tx][ty + p * 8]);
}

// V-part of qkvb -> vT[h][d][lp], lp = l + 32, zero-padded outside [0,LSEQ)
__global__ __launch_bounds__(256) void v_transpose(
    const short* __restrict__ qkvb, short* __restrict__ vT) {
  __shared__ short T[64][65];
  const int h = blockIdx.y, lt = blockIdx.x;   // lt over 33 tiles of 64
  const int lane = threadIdx.x & 63, ty = threadIdx.x >> 6;
#pragma unroll
  for (int p = 0; p < 16; ++p) {
    int r = ty + p * 4;                         // padded-l row in tile
    int l = lt * 64 + r - PADW;
    short v = 0;
    if ((unsigned)l < (unsigned)LSEQ)
      v = qkvb[(size_t)l * QKV_N + h * 192 + 128 + lane];
    T[r][lane] = v;
  }
  __syncthreads();
#pragma unroll
  for (int p = 0; p < 16; ++p) {
    int d = ty + p * 4;
    vT[((size_t)h * 64 + d) * LPAD + lt * 64 + lane] = T[lane][d];
  }
}

// ---------------------------------------------------------------------------
// m97-style bf16 MFMA GEMM: C[M,N] = A[M,K] @ Bt[N,K]^T (+bias).
// Tile BM x BN, BK=32; 4 waves 2x2; wave tile (BM/2)x(BN/2); 16x16x32 MFMA.
// global_load_lds width-16 staging.
// ---------------------------------------------------------------------------
template <int BM, int BN, bool OUT_BF16>
__global__ __launch_bounds__(256) void gemm_bf16(
    const short* __restrict__ A, const short* __restrict__ Bt,
    const float* __restrict__ bias, void* __restrict__ Cv,
    int M, int N, int K) {
  constexpr int MT = BM / 32;            // m-frags per wave
  constexpr int NT = BN / 32;            // n-frags per wave
  constexpr int ACH = BM / 64;           // A staging insts per wave
  constexpr int BCH = BN / 64;
  __shared__ short Alds[BM * 32];
  __shared__ short Blds[BN * 32];

  const int tid = threadIdx.x;
  const int wv = tid >> 6, lane = tid & 63;
  const int wm = wv >> 1, wn = wv & 1;
  const int lanelo = lane & 15, quad = lane >> 4;
  const int m0 = blockIdx.y * BM, n0 = blockIdx.x * BN;
  const int srow = lane >> 2, schk = lane & 3;   // 16 rows x 4 chunks of 16B

  f32x4 acc[MT][NT] = {};

  for (int k0 = 0; k0 < K; k0 += 32) {
#pragma unroll
    for (int c = 0; c < ACH; ++c) {
      int chunk = wv * ACH + c;
      const short* ga = A + (size_t)(m0 + chunk * 16 + srow) * K + k0 + schk * 8;
      __builtin_amdgcn_global_load_lds(GLB(ga), LDS(&Alds[chunk * 16 * 32]), 16, 0, 0);
    }
#pragma unroll
    for (int c = 0; c < BCH; ++c) {
      int chunk = wv * BCH + c;
      const short* gb = Bt + (size_t)(n0 + chunk * 16 + srow) * K + k0 + schk * 8;
      __builtin_amdgcn_global_load_lds(GLB(gb), LDS(&Blds[chunk * 16 * 32]), 16, 0, 0);
    }
    __syncthreads();

    short8 af[MT], bfr[NT];
#pragma unroll
    for (int mt = 0; mt < MT; ++mt)
      af[mt] = *(const short8*)&Alds[(wm * (MT * 16) + mt * 16 + lanelo) * 32 + quad * 8];
#pragma unroll
    for (int nt = 0; nt < NT; ++nt)
      bfr[nt] = *(const short8*)&Blds[(wn * (NT * 16) + nt * 16 + lanelo) * 32 + quad * 8];
#pragma unroll
    for (int mt = 0; mt < MT; ++mt)
#pragma unroll
      for (int nt = 0; nt < NT; ++nt)
        acc[mt][nt] = __builtin_amdgcn_mfma_f32_16x16x32_bf16(af[mt], bfr[nt], acc[mt][nt], 0, 0, 0);
    __syncthreads();
  }

#pragma unroll
  for (int mt = 0; mt < MT; ++mt)
#pragma unroll
    for (int nt = 0; nt < NT; ++nt) {
      int col = n0 + wn * (NT * 16) + nt * 16 + lanelo;
      float bv = OUT_BF16 ? 0.f : bias[col];
#pragma unroll
      for (int r = 0; r < 4; ++r) {
        int row = m0 + wm * (MT * 16) + mt * 16 + quad * 4 + r;
        if (OUT_BF16)
          ((short*)Cv)[(size_t)row * N + col] = f2bf(acc[mt][nt][r]);
        else
          ((float*)Cv)[(size_t)row * N + col] = acc[mt][nt][r] + bv;
      }
    }
}

// ---------------------------------------------------------------------------
// MFMA windowed attention, all-bf16 inputs. Block = 64 rows x 1 head.
// Wave wv owns rows [wv*16, wv*16+16). Span = 128 K/V rows from l0-32.
// S = Q.K^T (frags: b128 from global bf16), masked softmax, P via LDS
// (C-layout -> A-layout), O = P.V with V b-frags b128 from vT.
// ---------------------------------------------------------------------------
__global__ __launch_bounds__(256) void attn_mfma(
    const short* __restrict__ qkvb, const short* __restrict__ vT,
    short* __restrict__ attnb) {
  const int blk = blockIdx.x;
  const int h = blk % HEADS;
  const int l0 = (blk / HEADS) * 64;
  const int sb = l0 - PADW;

  const int tid = threadIdx.x;
  const int wv = tid >> 6, lane = tid & 63;
  const int lanelo = lane & 15, quad = lane >> 4;
  const int qoff = h * 192, koff = h * 192 + 64;

  __shared__ short P_lds[64 * 136];

  // Q a-frags: rows l0 + wv*16 + lanelo (always in-bounds)
  const short* qp = qkvb + (size_t)(l0 + wv * 16 + lanelo) * QKV_N + qoff;
  short8 aq0 = *(const short8*)(qp + quad * 8);
  short8 aq1 = *(const short8*)(qp + 32 + quad * 8);

  // ---- S = Q.K^T : 8 n-tiles x 2 k-steps
  f32x4 sacc[8] = {};
#pragma unroll
  for (int nt = 0; nt < 8; ++nt) {
    int gl = sb + nt * 16 + lanelo;
    short8 bk0 = {}, bk1 = {};
    if ((unsigned)gl < (unsigned)LSEQ) {
      const short* kp = qkvb + (size_t)gl * QKV_N + koff;
      bk0 = *(const short8*)(kp + quad * 8);
      bk1 = *(const short8*)(kp + 32 + quad * 8);
    }
    sacc[nt] = __builtin_amdgcn_mfma_f32_16x16x32_bf16(aq0, bk0, sacc[nt], 0, 0, 0);
    sacc[nt] = __builtin_amdgcn_mfma_f32_16x16x32_bf16(aq1, bk1, sacc[nt], 0, 0, 0);
  }

  // ---- masked softmax per row (row within strip = quad*4+r)
  float rmax[4] = {-1e30f, -1e30f, -1e30f, -1e30f};
#pragma unroll
  for (int nt = 0; nt < 8; ++nt)
#pragma unroll
    for (int r = 0; r < 4; ++r) {
      int li = wv * 16 + quad * 4 + r;
      int widx = nt * 16 + lanelo - li;
      float s = (widx >= 0 && widx <= 64) ? sacc[nt][r] * 0.125f : -1e30f;
      sacc[nt][r] = s;
      rmax[r] = fmaxf(rmax[r], s);
    }
#pragma unroll
  for (int r = 0; r < 4; ++r)
#pragma unroll
    for (int off = 1; off < 16; off <<= 1)
      rmax[r] = fmaxf(rmax[r], __shfl_xor(rmax[r], off));
  float rsum[4] = {0.f, 0.f, 0.f, 0.f};
#pragma unroll
  for (int nt = 0; nt < 8; ++nt)
#pragma unroll
    for (int r = 0; r < 4; ++r) {
      float p = __expf(sacc[nt][r] - rmax[r]);
      sacc[nt][r] = p;
      rsum[r] += p;
    }
#pragma unroll
  for (int r = 0; r < 4; ++r) {
#pragma unroll
    for (int off = 1; off < 16; off <<= 1)
      rsum[r] += __shfl_xor(rsum[r], off);
    rsum[r] = 1.f / rsum[r];
  }
#pragma unroll
  for (int nt = 0; nt < 8; ++nt)
#pragma unroll
    for (int r = 0; r < 4; ++r) {
      int row = wv * 16 + quad * 4 + r;
      P_lds[row * 136 + nt * 16 + lanelo] = f2bf(sacc[nt][r] * rsum[r]);
    }
  __syncthreads();

  // ---- O = P.V : 4 d-tiles x 4 k-steps of 32
  f32x4 oacc[4] = {};
#pragma unroll
  for (int ks = 0; ks < 4; ++ks) {
    short8 ap = *(const short8*)&P_lds[(wv * 16 + lanelo) * 136 + ks * 32 + quad * 8];
    int lp = l0 + ks * 32 + quad * 8;        // padded-l of first of 8 rows
#pragma unroll
    for (int nt = 0; nt < 4; ++nt) {
      int d = nt * 16 + lanelo;
      short8 bv = *(const short8*)&vT[((size_t)h * 64 + d) * LPAD + lp];
      oacc[nt] = __builtin_amdgcn_mfma_f32_16x16x32_bf16(ap, bv, oacc[nt], 0, 0, 0);
    }
  }

  // ---- store O bf16 [2048][768]
#pragma unroll
  for (int nt = 0; nt < 4; ++nt)
#pragma unroll
    for (int r = 0; r < 4; ++r) {
      int row = l0 + wv * 16 + quad * 4 + r;
      int col = h * 64 + nt * 16 + lanelo;
      attnb[(size_t)row * EMBED + col] = f2bf(oacc[nt][r]);
    }
}

extern "C" void kernel_launch(void* const* d_in, const int* in_sizes, int n_in,
                              void* d_out, int out_size, void* d_ws, size_t ws_size,
                              hipStream_t stream) {
  const float* x     = (const float*)d_in[0];   // [2048, 768]
  const float* w_qkv = (const float*)d_in[1];   // [768, 2304]
  const float* w_out = (const float*)d_in[2];   // [768, 768]
  const float* b_out = (const float*)d_in[3];   // [768]
  float* out = (float*)d_out;                   // [2048, 768]

  short *xb, *wqkvT, *woutT, *qkvb, *vT, *attnb;
  hipGetSymbolAddress((void**)&xb,    HIP_SYMBOL(g_xb));
  hipGetSymbolAddress((void**)&wqkvT, HIP_SYMBOL(g_wqkvT));
  hipGetSymbolAddress((void**)&woutT, HIP_SYMBOL(g_woutT));
  hipGetSymbolAddress((void**)&qkvb,  HIP_SYMBOL(g_qkvb));
  hipGetSymbolAddress((void**)&vT,    HIP_SYMBOL(g_vT));
  hipGetSymbolAddress((void**)&attnb, HIP_SYMBOL(g_attnb));

  // prep: casts + weight transposes
  cast_bf16<<<(LSEQ * EMBED) / (256 * 4), 256, 0, stream>>>(x, xb);
  transpose_cast<<<dim3(QKV_N / 32, EMBED / 32), 256, 0, stream>>>(w_qkv, wqkvT, EMBED, QKV_N);
  transpose_cast<<<dim3(EMBED / 32, EMBED / 32), 256, 0, stream>>>(w_out, woutT, EMBED, EMBED);

  // qkv = x @ w_qkv  -> bf16
  gemm_bf16<128, 128, true><<<dim3(QKV_N / 128, LSEQ / 128), 256, 0, stream>>>(
      xb, wqkvT, nullptr, qkvb, LSEQ, QKV_N, EMBED);

  // V^T with zero pads
  v_transpose<<<dim3(LPAD / 64, HEADS), 256, 0, stream>>>(qkvb, vT);

  // windowed attention -> attnb (bf16)
  attn_mfma<<<(LSEQ / 64) * HEADS, 256, 0, stream>>>(qkvb, vT, attnb);

  // out = attn @ w_out + b_out  (fp32)
  gemm_bf16<128, 64, false><<<dim3(EMBED / 64, LSEQ / 128), 256, 0, stream>>>(
      attnb, woutT, b_out, out, LSEQ, EMBED, EMBED);
}

// Round 4
// 122.931 us; speedup vs baseline: 1.1251x; 1.1251x over previous
//
#include <hip/hip_runtime.h>
#include <hip/hip_bf16.h>

#define HEADS 12
#define HD 64
#define PADW 32
#define EMBED 768
#define LSEQ 2048
#define QKV_N (3 * HEADS * HD)   // 2304
#define LPAD (LSEQ + 64)         // 2112

typedef short short8 __attribute__((ext_vector_type(8)));
typedef short short4v __attribute__((ext_vector_type(4)));
typedef float f32x4 __attribute__((ext_vector_type(4)));

// Static scratch, fully overwritten every call (poison-safe).
__device__ short g_xb[LSEQ * EMBED];        // x bf16             [2048][768]
__device__ short g_wqkvT[QKV_N * EMBED];    // w_qkv^T bf16       [2304][768]
__device__ short g_woutT[EMBED * EMBED];    // w_out^T bf16       [768][768]
__device__ short g_qkvb[LSEQ * QKV_N];      // qkv bf16           [2048][2304]
__device__ short g_vT[HEADS * HD * LPAD];   // V^T bf16, 0-padded [768][2112]
__device__ short g_attnb[LSEQ * EMBED];     // attn out bf16      [2048][768]

__device__ __forceinline__ short f2bf(float f) {
  unsigned x = __builtin_bit_cast(unsigned, f);
  x += 0x7fffu + ((x >> 16) & 1u);   // RNE
  return (short)(x >> 16);
}

#define GLB(p) ((const __attribute__((address_space(1))) void*)(p))
#define LDS(p) ((__attribute__((address_space(3))) void*)(p))

// ---------------------------------------------------------------------------
// prep: job A = cast x, job B/C = weight transposes, job D = zero vT pads.
// One dispatch instead of four.
// ---------------------------------------------------------------------------
#define PREP_A 1536              // (2048*768/4)/256
#define PREP_B 1728              // w_qkv: 72 x 24 tiles of 32x32
#define PREP_C 576               // w_out: 24 x 24
#define PREP_D 24                // vT pad zero: 768*64 shorts / (256*8)

__global__ __launch_bounds__(256) void prep(
    const float* __restrict__ x, const float* __restrict__ w_qkv,
    const float* __restrict__ w_out, short* __restrict__ xb,
    short* __restrict__ wqkvT, short* __restrict__ woutT,
    short* __restrict__ vT) {
  __shared__ float T[32][33];
  const int b = blockIdx.x, tid = threadIdx.x;
  if (b < PREP_A) {
    int i = b * 256 + tid;
    float4 v = ((const float4*)x)[i];
    short4v o;
    o[0] = f2bf(v.x); o[1] = f2bf(v.y); o[2] = f2bf(v.z); o[3] = f2bf(v.w);
    ((short4v*)xb)[i] = o;
  } else if (b < PREP_A + PREP_B + PREP_C) {
    const float* W; short* WT; int N, bx, by;
    if (b < PREP_A + PREP_B) {
      int t = b - PREP_A; W = w_qkv; WT = wqkvT; N = QKV_N; bx = t % 72; by = t / 72;
    } else {
      int t = b - PREP_A - PREP_B; W = w_out; WT = woutT; N = EMBED; bx = t % 24; by = t / 24;
    }
    const int K = EMBED;
    int tx = tid & 31, ty = tid >> 5;
    int n0 = bx * 32, k0 = by * 32;
#pragma unroll
    for (int p = 0; p < 4; ++p)
      T[ty + p * 8][tx] = W[(size_t)(k0 + ty + p * 8) * N + n0 + tx];
    __syncthreads();
#pragma unroll
    for (int p = 0; p < 4; ++p)
      WT[(size_t)(n0 + ty + p * 8) * K + k0 + tx] = f2bf(T[tx][ty + p * 8]);
  } else {
    int j = (b - PREP_A - PREP_B - PREP_C) * 256 + tid;
    int hd = j >> 3, side = (j >> 2) & 1, off = (j & 3) * 8;
    short8 z = {};
    *(short8*)&vT[(size_t)hd * LPAD + side * 2080 + off] = z;
  }
}

// ---------------------------------------------------------------------------
// bf16 MFMA GEMM: C[M,N] = A[M,K] @ Bt[N,K]^T (+bias). BK=32, 4 waves 2x2.
// Coalesced epilogue through LDS. FUSE_VT scatters V tiles into g_vT.
// ---------------------------------------------------------------------------
template <int BM, int BN, bool OUT_BF16, bool FUSE_VT>
__global__ __launch_bounds__(256) void gemm_bf16(
    const short* __restrict__ A, const short* __restrict__ Bt,
    const float* __restrict__ bias, void* __restrict__ Cv,
    short* __restrict__ vT, int M, int N, int K) {
  constexpr int MT = BM / 32, NT = BN / 32;
  constexpr int ACH = BM / 64, BCH = BN / 64;
  constexpr int STAGE = (BM + BN) * 32;                        // shorts
  constexpr int EPI = OUT_BF16 ? BM * (BN + 16) : BM * (BN + 8) * 2;
  constexpr int LDSZ = STAGE > EPI ? STAGE : EPI;
  __shared__ __align__(16) short lds[LDSZ];
  short* Alds = lds;
  short* Blds = lds + BM * 32;

  const int tid = threadIdx.x;
  const int wv = tid >> 6, lane = tid & 63;
  const int wm = wv >> 1, wn = wv & 1;
  const int lanelo = lane & 15, quad = lane >> 4;
  const int m0 = blockIdx.y * BM, n0 = blockIdx.x * BN;
  const int srow = lane >> 2, schk = lane & 3;

  f32x4 acc[MT][NT] = {};

  for (int k0 = 0; k0 < K; k0 += 32) {
#pragma unroll
    for (int c = 0; c < ACH; ++c) {
      int chunk = wv * ACH + c;
      const short* ga = A + (size_t)(m0 + chunk * 16 + srow) * K + k0 + schk * 8;
      __builtin_amdgcn_global_load_lds(GLB(ga), LDS(&Alds[chunk * 16 * 32]), 16, 0, 0);
    }
#pragma unroll
    for (int c = 0; c < BCH; ++c) {
      int chunk = wv * BCH + c;
      const short* gb = Bt + (size_t)(n0 + chunk * 16 + srow) * K + k0 + schk * 8;
      __builtin_amdgcn_global_load_lds(GLB(gb), LDS(&Blds[chunk * 16 * 32]), 16, 0, 0);
    }
    __syncthreads();

    short8 af[MT], bfr[NT];
#pragma unroll
    for (int mt = 0; mt < MT; ++mt)
      af[mt] = *(const short8*)&Alds[(wm * (MT * 16) + mt * 16 + lanelo) * 32 + quad * 8];
#pragma unroll
    for (int nt = 0; nt < NT; ++nt)
      bfr[nt] = *(const short8*)&Blds[(wn * (NT * 16) + nt * 16 + lanelo) * 32 + quad * 8];
#pragma unroll
    for (int mt = 0; mt < MT; ++mt)
#pragma unroll
      for (int nt = 0; nt < NT; ++nt)
        acc[mt][nt] = __builtin_amdgcn_mfma_f32_16x16x32_bf16(af[mt], bfr[nt], acc[mt][nt], 0, 0, 0);
    __syncthreads();
  }

  // ---- fused V^T scatter (V tiles only: n0 % 192 == 128) ----
  if (FUSE_VT && (n0 % 192) == 128) {
    int h = n0 / 192;
#pragma unroll
    for (int mt = 0; mt < MT; ++mt)
#pragma unroll
      for (int nt = 0; nt < NT; ++nt) {
        int d = wn * (NT * 16) + nt * 16 + lanelo;
        int row0 = m0 + wm * (MT * 16) + mt * 16 + quad * 4;
        short4v o;
#pragma unroll
        for (int r = 0; r < 4; ++r) o[r] = f2bf(acc[mt][nt][r]);
        *(short4v*)&vT[(size_t)(h * 64 + d) * LPAD + PADW + row0] = o;
      }
  }

  // ---- coalesced epilogue through LDS ----
  if (OUT_BF16) {
    constexpr int ST = BN + 16;            // shorts; 16B-aligned rows, 2-way reads
#pragma unroll
    for (int mt = 0; mt < MT; ++mt)
#pragma unroll
      for (int nt = 0; nt < NT; ++nt) {
        int rloc = wm * (MT * 16) + mt * 16 + quad * 4;
        int cloc = wn * (NT * 16) + nt * 16 + lanelo;
#pragma unroll
        for (int r = 0; r < 4; ++r)
          lds[(rloc + r) * ST + cloc] = f2bf(acc[mt][nt][r]);
      }
    __syncthreads();
    constexpr int TPR = BN / 8, RPP = 256 / TPR;
    short* Cc = (short*)Cv;
#pragma unroll
    for (int rp = 0; rp < BM; rp += RPP) {
      int row = rp + tid / TPR, seg = tid % TPR;
      short8 vv = *(const short8*)&lds[row * ST + seg * 8];
      *(short8*)&Cc[(size_t)(m0 + row) * N + n0 + seg * 8] = vv;
    }
  } else {
    constexpr int ST = BN + 8;             // floats
    float* fl = (float*)lds;
#pragma unroll
    for (int mt = 0; mt < MT; ++mt)
#pragma unroll
      for (int nt = 0; nt < NT; ++nt) {
        int rloc = wm * (MT * 16) + mt * 16 + quad * 4;
        int cloc = wn * (NT * 16) + nt * 16 + lanelo;
#pragma unroll
        for (int r = 0; r < 4; ++r)
          fl[(rloc + r) * ST + cloc] = acc[mt][nt][r];
      }
    __syncthreads();
    constexpr int TPR = BN / 4, RPP = 256 / TPR;
    float* Cc = (float*)Cv;
#pragma unroll
    for (int rp = 0; rp < BM; rp += RPP) {
      int row = rp + tid / TPR, seg = tid % TPR;
      float4 vv = *(const float4*)&fl[row * ST + seg * 4];
      float4 bb = *(const float4*)&bias[n0 + seg * 4];
      vv.x += bb.x; vv.y += bb.y; vv.z += bb.z; vv.w += bb.w;
      *(float4*)&Cc[(size_t)(m0 + row) * N + n0 + seg * 4] = vv;
    }
  }
}

// ---------------------------------------------------------------------------
// MFMA windowed attention. Block = 64 rows x 1 head; 4 waves, 16-row strips.
// Span = 128 K/V rows from l0-32. Zero pads reproduce reference semantics.
// ---------------------------------------------------------------------------
__global__ __launch_bounds__(256) void attn_mfma(
    const short* __restrict__ qkvb, const short* __restrict__ vT,
    short* __restrict__ attnb) {
  const int blk = blockIdx.x;
  const int h = blk % HEADS;
  const int l0 = (blk / HEADS) * 64;
  const int sb = l0 - PADW;

  const int tid = threadIdx.x;
  const int wv = tid >> 6, lane = tid & 63;
  const int lanelo = lane & 15, quad = lane >> 4;
  const int qoff = h * 192, koff = h * 192 + 64;

  __shared__ __align__(16) short P_lds[64 * 136];

  // Q a-frags: rows l0 + wv*16 + lanelo
  const short* qp = qkvb + (size_t)(l0 + wv * 16 + lanelo) * QKV_N + qoff;
  short8 aq0 = *(const short8*)(qp + quad * 8);
  short8 aq1 = *(const short8*)(qp + 32 + quad * 8);

  // ---- S = Q.K^T
  f32x4 sacc[8] = {};
#pragma unroll
  for (int nt = 0; nt < 8; ++nt) {
    int gl = sb + nt * 16 + lanelo;
    short8 bk0 = {}, bk1 = {};
    if ((unsigned)gl < (unsigned)LSEQ) {
      const short* kp = qkvb + (size_t)gl * QKV_N + koff;
      bk0 = *(const short8*)(kp + quad * 8);
      bk1 = *(const short8*)(kp + 32 + quad * 8);
    }
    sacc[nt] = __builtin_amdgcn_mfma_f32_16x16x32_bf16(aq0, bk0, sacc[nt], 0, 0, 0);
    sacc[nt] = __builtin_amdgcn_mfma_f32_16x16x32_bf16(aq1, bk1, sacc[nt], 0, 0, 0);
  }

  // ---- masked softmax per row
  float rmax[4] = {-1e30f, -1e30f, -1e30f, -1e30f};
#pragma unroll
  for (int nt = 0; nt < 8; ++nt)
#pragma unroll
    for (int r = 0; r < 4; ++r) {
      int li = wv * 16 + quad * 4 + r;
      int widx = nt * 16 + lanelo - li;
      float s = (widx >= 0 && widx <= 64) ? sacc[nt][r] * 0.125f : -1e30f;
      sacc[nt][r] = s;
      rmax[r] = fmaxf(rmax[r], s);
    }
#pragma unroll
  for (int r = 0; r < 4; ++r)
#pragma unroll
    for (int off = 1; off < 16; off <<= 1)
      rmax[r] = fmaxf(rmax[r], __shfl_xor(rmax[r], off));
  float rsum[4] = {0.f, 0.f, 0.f, 0.f};
#pragma unroll
  for (int nt = 0; nt < 8; ++nt)
#pragma unroll
    for (int r = 0; r < 4; ++r) {
      float p = __expf(sacc[nt][r] - rmax[r]);
      sacc[nt][r] = p;
      rsum[r] += p;
    }
#pragma unroll
  for (int r = 0; r < 4; ++r) {
#pragma unroll
    for (int off = 1; off < 16; off <<= 1)
      rsum[r] += __shfl_xor(rsum[r], off);
    rsum[r] = 1.f / rsum[r];
  }
#pragma unroll
  for (int nt = 0; nt < 8; ++nt)
#pragma unroll
    for (int r = 0; r < 4; ++r) {
      int row = wv * 16 + quad * 4 + r;
      P_lds[row * 136 + nt * 16 + lanelo] = f2bf(sacc[nt][r] * rsum[r]);
    }
  __syncthreads();

  // ---- O = P.V
  f32x4 oacc[4] = {};
#pragma unroll
  for (int ks = 0; ks < 4; ++ks) {
    short8 ap = *(const short8*)&P_lds[(wv * 16 + lanelo) * 136 + ks * 32 + quad * 8];
    int lp = l0 + ks * 32 + quad * 8;
#pragma unroll
    for (int nt = 0; nt < 4; ++nt) {
      int d = nt * 16 + lanelo;
      short8 bv = *(const short8*)&vT[((size_t)h * 64 + d) * LPAD + lp];
      oacc[nt] = __builtin_amdgcn_mfma_f32_16x16x32_bf16(ap, bv, oacc[nt], 0, 0, 0);
    }
  }

  // ---- coalesced O store through LDS (stride 80 shorts)
  __syncthreads();                          // all P reads done before overwrite
#pragma unroll
  for (int nt = 0; nt < 4; ++nt)
#pragma unroll
    for (int r = 0; r < 4; ++r) {
      int row = wv * 16 + quad * 4 + r;
      P_lds[row * 80 + nt * 16 + lanelo] = f2bf(oacc[nt][r]);
    }
  __syncthreads();
#pragma unroll
  for (int rp = 0; rp < 64; rp += 32) {
    int row = rp + tid / 8, seg = tid % 8;
    short8 vv = *(const short8*)&P_lds[row * 80 + seg * 8];
    *(short8*)&attnb[(size_t)(l0 + row) * EMBED + h * 64 + seg * 8] = vv;
  }
}

extern "C" void kernel_launch(void* const* d_in, const int* in_sizes, int n_in,
                              void* d_out, int out_size, void* d_ws, size_t ws_size,
                              hipStream_t stream) {
  const float* x     = (const float*)d_in[0];   // [2048, 768]
  const float* w_qkv = (const float*)d_in[1];   // [768, 2304]
  const float* w_out = (const float*)d_in[2];   // [768, 768]
  const float* b_out = (const float*)d_in[3];   // [768]
  float* out = (float*)d_out;                   // [2048, 768]

  short *xb, *wqkvT, *woutT, *qkvb, *vT, *attnb;
  hipGetSymbolAddress((void**)&xb,    HIP_SYMBOL(g_xb));
  hipGetSymbolAddress((void**)&wqkvT, HIP_SYMBOL(g_wqkvT));
  hipGetSymbolAddress((void**)&woutT, HIP_SYMBOL(g_woutT));
  hipGetSymbolAddress((void**)&qkvb,  HIP_SYMBOL(g_qkvb));
  hipGetSymbolAddress((void**)&vT,    HIP_SYMBOL(g_vT));
  hipGetSymbolAddress((void**)&attnb, HIP_SYMBOL(g_attnb));

  // 1) fused prep (cast x, transpose weights, zero vT pads)
  prep<<<PREP_A + PREP_B + PREP_C + PREP_D, 256, 0, stream>>>(
      x, w_qkv, w_out, xb, wqkvT, woutT, vT);

  // 2) qkv = x @ w_qkv -> bf16, with fused V^T scatter. 576 blocks.
  gemm_bf16<128, 64, true, true><<<dim3(QKV_N / 64, LSEQ / 128), 256, 0, stream>>>(
      xb, wqkvT, nullptr, qkvb, vT, LSEQ, QKV_N, EMBED);

  // 3) windowed attention -> attnb (bf16). 384 blocks.
  attn_mfma<<<(LSEQ / 64) * HEADS, 256, 0, stream>>>(qkvb, vT, attnb);

  // 4) out = attn @ w_out + b_out (fp32). 384 blocks.
  gemm_bf16<64, 64, false, false><<<dim3(EMBED / 64, LSEQ / 64), 256, 0, stream>>>(
      attnb, woutT, b_out, out, nullptr, LSEQ, EMBED, EMBED);
}